// Round 4
// baseline (196.167 us; speedup 1.0000x reference)
//
#include <hip/hip_runtime.h>
#include <hip/hip_bf16.h>
#include <math.h>

typedef __attribute__((ext_vector_type(8))) short short8;
typedef __attribute__((ext_vector_type(4))) float f32x4;

#define B_    2
#define T_    128
#define D_    256
#define H_    8
#define F_    64
#define C_    512
#define TEMB_ 512

static __device__ __forceinline__ unsigned short f2bf(float f) {
  __hip_bfloat16 h = __float2bfloat16(f);
  return reinterpret_cast<unsigned short&>(h);
}
static __device__ __forceinline__ unsigned int pk2(float a, float b) {
  return (unsigned int)f2bf(a) | ((unsigned int)f2bf(b) << 16);
}

// ---------------------------------------------------------------------------
// k_prep: w_out fp32 [512][512] -> wsw bf16 in MFMA-B-fragment order:
// slot (oi*16+kjg)*64+lane holds 8 bf16 at o=oi*16+(lane&15),
// c=kjg*32+(lane>>4)*8.. ; w_dist [512][3] -> column-major wdT[3][512].
// ---------------------------------------------------------------------------
__global__ __launch_bounds__(256) void k_prep(
    const float* __restrict__ w_out, const float* __restrict__ w_dist,
    short* __restrict__ wsw, float* __restrict__ wdT)
{
  int gid = blockIdx.x * 256 + threadIdx.x;
  for (int s = gid; s < 32768; s += 16384) {
    int oi = s >> 10, rem = s & 1023, kjg = rem >> 6, l = rem & 63;
    int o = oi * 16 + (l & 15), c = kjg * 32 + (l >> 4) * 8;
    const float* src = w_out + (size_t)o * C_ + c;
    float4 a = *reinterpret_cast<const float4*>(src);
    float4 b = *reinterpret_cast<const float4*>(src + 4);
    uint4 v; v.x = pk2(a.x, a.y); v.y = pk2(a.z, a.w);
    v.z = pk2(b.x, b.y); v.w = pk2(b.z, b.w);
    *reinterpret_cast<uint4*>(wsw + (size_t)s * 8) = v;
  }
  if (gid < C_) {
    wdT[0 * C_ + gid] = w_dist[gid * 3 + 0];
    wdT[1 * C_ + gid] = w_dist[gid * 3 + 1];
    wdT[2 * C_ + gid] = w_dist[gid * 3 + 2];
  }
}

// ---------------------------------------------------------------------------
// k_base: base[bt][c] = temb @ w_time^T + b_time + b_dist   (verified R1-R3)
// ---------------------------------------------------------------------------
__global__ __launch_bounds__(256) void k_base(
    const float* __restrict__ temb, const float* __restrict__ w_time,
    const float* __restrict__ b_time, const float* __restrict__ b_dist,
    float* __restrict__ base)
{
  __shared__ float tt[32][64];
  __shared__ float wt[64][65];
  const int bt0 = blockIdx.x * 32;
  const int c0  = blockIdx.y * 64;
  const int tid = threadIdx.x;
  const int cl  = tid & 63;
  const int g   = tid >> 6;
  float acc[8] = {0.f,0.f,0.f,0.f,0.f,0.f,0.f,0.f};

  for (int k0 = 0; k0 < TEMB_; k0 += 64) {
#pragma unroll
    for (int i = 0; i < 8; ++i) {
      int idx = tid + i * 256; int r = idx >> 6, k = idx & 63;
      tt[r][k] = temb[(size_t)(bt0 + r) * TEMB_ + k0 + k];
    }
#pragma unroll
    for (int i = 0; i < 16; ++i) {
      int idx = tid + i * 256; int r = idx >> 6, k = idx & 63;
      wt[r][k] = w_time[(size_t)(c0 + r) * TEMB_ + k0 + k];
    }
    __syncthreads();
#pragma unroll
    for (int k = 0; k < 64; ++k) {
      float w = wt[cl][k];
#pragma unroll
      for (int j = 0; j < 8; ++j) acc[j] += tt[g + 4 * j][k] * w;
    }
    __syncthreads();
  }
  float bb = b_time[c0 + cl] + b_dist[c0 + cl];
#pragma unroll
  for (int j = 0; j < 8; ++j)
    base[(size_t)(bt0 + g + 4 * j) * C_ + c0 + cl] = acc[j] + bb;
}

// ---------------------------------------------------------------------------
// k_fused: one block per (b,t), 1024 threads (16 waves, 4/SIMD), ~149 KB LDS.
// Phase 1: R[s=128][o=512] = silu(base+df.wd) @ w_out^T + b_out; MFMA
//   16x16x32 bf16; wave tile 64(M)x64(N), waves 2(wm)x8(wn); B-frags direct
//   from global wsw (L2-resident); R -> LDS bf16, XOR-swizzled per 16B
//   granule g' = (g&~7)|((g^s)&7).
// Phase 2: 2 waves per h (d halves); out[d][s] = qk[d][f].R[s][h*64+f];
//   R B-frags resident in 64 VGPRs; qk in 16-d chunks, next-chunk prefetch.
// VGPR capped at 128 by __launch_bounds__(1024,4) -> 16 waves/CU.
// ---------------------------------------------------------------------------
__global__ __launch_bounds__(1024, 4) void k_fused(
    const float* __restrict__ qk, const float* __restrict__ pd,
    const float* __restrict__ base, const float* __restrict__ wdT,
    const short* __restrict__ wsw, const float* __restrict__ b_out,
    float* __restrict__ out)
{
  __shared__ __align__(16) unsigned short Rlds[T_ * C_];  // 128 KB
  __shared__ __align__(16) short At[8192];                // 16 KB
  __shared__ float df[3][T_];

  const int bt = blockIdx.x;
  const int b  = bt >> 7;
  const int t  = bt & 127;
  const int tid  = threadIdx.x;
  const int lane = tid & 63;
  const int wave = tid >> 6;          // 0..15
  const int lanem = lane & 15;
  const int laneg = lane >> 4;

  if (tid < T_) {
    float p = pd[((size_t)b * T_ + t) * T_ + tid];
    df[0][tid] = log1pf(fmaxf(p, 0.f));
    df[1][tid] = log1pf(fmaxf(-p, 0.f));
    df[2][tid] = (p == 0.f) ? 1.f : 0.f;
  }

  // ---------------- Phase 1 ----------------
  const int wm = wave >> 3;           // 0..1  s-half (64 rows)
  const int wn = wave & 7;            // 0..7  o-slice (64 cols)

  // A-tile producer mapping: 1024 threads x 8 elems = 128s x 64c per k-tile
  const int s_low = tid & 15;
  const int cg    = (tid >> 4) & 7;   // c-group (8 c each)
  const int si    = tid >> 7;         // 0..7
  const int kjA   = cg >> 2;
  const int cgl   = cg & 3;
  const int laneslotA = s_low + 16 * cgl;
  const int sA    = si * 16 + s_low;
  const float* baserow = base + (size_t)bt * C_;

  f32x4 acc[4][4];
#pragma unroll
  for (int mi = 0; mi < 4; ++mi)
#pragma unroll
    for (int ni = 0; ni < 4; ++ni) acc[mi][ni] = (f32x4){0.f, 0.f, 0.f, 0.f};

  for (int kt = 0; kt < 8; ++kt) {
    __syncthreads();   // prev-iter At consumers done (covers df on kt=0)
    short8 b0[4], b1[4];
#pragma unroll
    for (int ni = 0; ni < 4; ++ni)     // kj=0 B-frags (L2)
      b0[ni] = *reinterpret_cast<const short8*>(
          wsw + ((size_t)((wn * 4 + ni) * 16 + kt * 2 + 0) * 64 + lane) * 8);
    // ---- produce A tile: silu(base + df.wd), two 4-channel halves ----
    {
      const int cglob = kt * 64 + cg * 8;
      const float d0 = df[0][sA], d1 = df[1][sA], d2 = df[2][sA];
      uint4 v;
      {
        float4 bs = *reinterpret_cast<const float4*>(baserow + cglob);
        float4 wa = *reinterpret_cast<const float4*>(wdT + cglob);
        float4 wb = *reinterpret_cast<const float4*>(wdT + C_ + cglob);
        float4 wc = *reinterpret_cast<const float4*>(wdT + 2 * C_ + cglob);
        float x0 = bs.x + d0 * wa.x + d1 * wb.x + d2 * wc.x;
        float x1 = bs.y + d0 * wa.y + d1 * wb.y + d2 * wc.y;
        float x2 = bs.z + d0 * wa.z + d1 * wb.z + d2 * wc.z;
        float x3 = bs.w + d0 * wa.w + d1 * wb.w + d2 * wc.w;
        x0 = x0 / (1.f + __expf(-x0)); x1 = x1 / (1.f + __expf(-x1));
        x2 = x2 / (1.f + __expf(-x2)); x3 = x3 / (1.f + __expf(-x3));
        v.x = pk2(x0, x1); v.y = pk2(x2, x3);
      }
      {
        float4 bs = *reinterpret_cast<const float4*>(baserow + cglob + 4);
        float4 wa = *reinterpret_cast<const float4*>(wdT + cglob + 4);
        float4 wb = *reinterpret_cast<const float4*>(wdT + C_ + cglob + 4);
        float4 wc = *reinterpret_cast<const float4*>(wdT + 2 * C_ + cglob + 4);
        float x0 = bs.x + d0 * wa.x + d1 * wb.x + d2 * wc.x;
        float x1 = bs.y + d0 * wa.y + d1 * wb.y + d2 * wc.y;
        float x2 = bs.z + d0 * wa.z + d1 * wb.z + d2 * wc.z;
        float x3 = bs.w + d0 * wa.w + d1 * wb.w + d2 * wc.w;
        x0 = x0 / (1.f + __expf(-x0)); x1 = x1 / (1.f + __expf(-x1));
        x2 = x2 / (1.f + __expf(-x2)); x3 = x3 / (1.f + __expf(-x3));
        v.z = pk2(x0, x1); v.w = pk2(x2, x3);
      }
      *reinterpret_cast<uint4*>(&At[((si * 2 + kjA) * 64 + laneslotA) * 8]) = v;
    }
#pragma unroll
    for (int ni = 0; ni < 4; ++ni)     // kj=1 B-frags overlap the barrier
      b1[ni] = *reinterpret_cast<const short8*>(
          wsw + ((size_t)((wn * 4 + ni) * 16 + kt * 2 + 1) * 64 + lane) * 8);
    __syncthreads();
    // ---- MFMA ----
    {
      short8 a[4];
#pragma unroll
      for (int mi = 0; mi < 4; ++mi)
        a[mi] = *reinterpret_cast<const short8*>(
            &At[(((wm * 4 + mi) * 2 + 0) * 64 + lane) * 8]);
#pragma unroll
      for (int ni = 0; ni < 4; ++ni)
#pragma unroll
        for (int mi = 0; mi < 4; ++mi)
          acc[mi][ni] = __builtin_amdgcn_mfma_f32_16x16x32_bf16(
              a[mi], b0[ni], acc[mi][ni], 0, 0, 0);
#pragma unroll
      for (int mi = 0; mi < 4; ++mi)
        a[mi] = *reinterpret_cast<const short8*>(
            &At[(((wm * 4 + mi) * 2 + 1) * 64 + lane) * 8]);
#pragma unroll
      for (int ni = 0; ni < 4; ++ni)
#pragma unroll
        for (int mi = 0; mi < 4; ++mi)
          acc[mi][ni] = __builtin_amdgcn_mfma_f32_16x16x32_bf16(
              a[mi], b1[ni], acc[mi][ni], 0, 0, 0);
    }
  }

  // ---- epilogue: + b_out, bf16, swizzled store into Rlds ----
#pragma unroll
  for (int ni = 0; ni < 4; ++ni) {
    const int o  = wn * 64 + ni * 16 + lanem;
    const float bo = b_out[o];
    const int g  = o >> 3;
#pragma unroll
    for (int mi = 0; mi < 4; ++mi) {
#pragma unroll
      for (int reg = 0; reg < 4; ++reg) {
        int s  = wm * 64 + mi * 16 + laneg * 4 + reg;
        int gp = (g & ~7) | ((g ^ s) & 7);
        Rlds[s * 512 + gp * 8 + (o & 7)] = f2bf(acc[mi][ni][reg] + bo);
      }
    }
  }

  // ---------------- Phase 2: 2 waves per h ----------------
  const int h  = wave >> 1;
  const int dh = wave & 1;            // d-half: 0 -> 0..127, 1 -> 128..255
  const size_t HTF = (size_t)H_ * T_ * F_;   // 65536
  const size_t HTT = (size_t)H_ * T_ * T_;   // 131072
  const float* qkb = qk + (size_t)b * D_ * HTF + (size_t)h * T_ * F_ + (size_t)t * F_;
  float* outb = out + (size_t)b * D_ * HTT + (size_t)h * T_ * T_ + (size_t)t * T_;

  // prefetch chunk 0 (qk independent of Rlds -> before barrier)
  float4 buf[4];
  {
    const float* src = qkb + (size_t)(dh * 128 + lanem) * HTF + laneg * 8;
    buf[0] = *reinterpret_cast<const float4*>(src);
    buf[1] = *reinterpret_cast<const float4*>(src + 4);
    buf[2] = *reinterpret_cast<const float4*>(src + 32);
    buf[3] = *reinterpret_cast<const float4*>(src + 36);
  }
  __syncthreads();   // Rlds ready

  short8 brf[2][8];                    // R B-frags, resident across d-loop
#pragma unroll
  for (int kj = 0; kj < 2; ++kj)
#pragma unroll
    for (int ni = 0; ni < 8; ++ni) {
      int s  = ni * 16 + lanem;
      int g  = h * 8 + kj * 4 + laneg;
      int gp = (g & ~7) | ((g ^ s) & 7);
      brf[kj][ni] = *reinterpret_cast<const short8*>(&Rlds[s * 512 + gp * 8]);
    }

  for (int cc = 0; cc < 8; ++cc) {
    const int dbase = dh * 128 + cc * 16;
    // convert current chunk
    short8 av0, av1;
    {
      union { uint4 u; short8 s; } cv;
      cv.u.x = pk2(buf[0].x, buf[0].y); cv.u.y = pk2(buf[0].z, buf[0].w);
      cv.u.z = pk2(buf[1].x, buf[1].y); cv.u.w = pk2(buf[1].z, buf[1].w);
      av0 = cv.s;
      cv.u.x = pk2(buf[2].x, buf[2].y); cv.u.y = pk2(buf[2].z, buf[2].w);
      cv.u.z = pk2(buf[3].x, buf[3].y); cv.u.w = pk2(buf[3].z, buf[3].w);
      av1 = cv.s;
    }
    // issue next-chunk loads (overlap with MFMA + stores)
    if (cc < 7) {
      const float* src = qkb + (size_t)(dbase + 16 + lanem) * HTF + laneg * 8;
      buf[0] = *reinterpret_cast<const float4*>(src);
      buf[1] = *reinterpret_cast<const float4*>(src + 4);
      buf[2] = *reinterpret_cast<const float4*>(src + 32);
      buf[3] = *reinterpret_cast<const float4*>(src + 36);
    }
    f32x4 ac[8];
#pragma unroll
    for (int ni = 0; ni < 8; ++ni) ac[ni] = (f32x4){0.f, 0.f, 0.f, 0.f};
#pragma unroll
    for (int ni = 0; ni < 8; ++ni)
      ac[ni] = __builtin_amdgcn_mfma_f32_16x16x32_bf16(av0, brf[0][ni], ac[ni], 0, 0, 0);
#pragma unroll
    for (int ni = 0; ni < 8; ++ni)
      ac[ni] = __builtin_amdgcn_mfma_f32_16x16x32_bf16(av1, brf[1][ni], ac[ni], 0, 0, 0);
#pragma unroll
    for (int reg = 0; reg < 4; ++reg) {
      float* row = outb + (size_t)(dbase + laneg * 4 + reg) * HTT;
#pragma unroll
      for (int ni = 0; ni < 8; ++ni)
        row[ni * 16 + lanem] = ac[ni][reg];
    }
  }
}

extern "C" void kernel_launch(void* const* d_in, const int* in_sizes, int n_in,
                              void* d_out, int out_size, void* d_ws, size_t ws_size,
                              hipStream_t stream) {
  const float* qk     = (const float*)d_in[0];
  const float* pd     = (const float*)d_in[1];
  const float* temb   = (const float*)d_in[2];
  const float* w_dist = (const float*)d_in[3];
  const float* b_dist = (const float*)d_in[4];
  const float* w_time = (const float*)d_in[5];
  const float* b_time = (const float*)d_in[6];
  const float* w_out  = (const float*)d_in[7];
  const float* b_out  = (const float*)d_in[8];
  float* out = (float*)d_out;

  char* ws = (char*)d_ws;
  float* base = (float*)(ws);              // 524288 B
  float* wdT  = (float*)(ws + 524288);     //   6144 B (8 KB slot)
  short* wsw  = (short*)(ws + 532480);     // 524288 B

  hipLaunchKernelGGL(k_prep, dim3(64), dim3(256), 0, stream,
                     w_out, w_dist, wsw, wdT);
  hipLaunchKernelGGL(k_base, dim3(8, 8), dim3(256), 0, stream,
                     temb, w_time, b_time, b_dist, base);
  hipLaunchKernelGGL(k_fused, dim3(B_ * T_), dim3(1024), 0, stream,
                     qk, pd, base, wdT, wsw, b_out, out);
}

// Round 5
// 192.150 us; speedup vs baseline: 1.0209x; 1.0209x over previous
//
#include <hip/hip_runtime.h>
#include <hip/hip_bf16.h>
#include <math.h>

typedef __attribute__((ext_vector_type(8))) short short8;
typedef __attribute__((ext_vector_type(4))) float f32x4;

#define B_    2
#define T_    128
#define D_    256
#define H_    8
#define F_    64
#define C_    512
#define TEMB_ 512

static __device__ __forceinline__ unsigned short f2bf(float f) {
  __hip_bfloat16 h = __float2bfloat16(f);
  return reinterpret_cast<unsigned short&>(h);
}
static __device__ __forceinline__ unsigned int pk2(float a, float b) {
  return (unsigned int)f2bf(a) | ((unsigned int)f2bf(b) << 16);
}

// ---------------------------------------------------------------------------
// k_prep: w_out fp32 [512][512] -> wsw bf16 in MFMA-B-fragment order (R2-R4
// verified). w_dist [512][3] -> column-major wdT[3][512].
// ---------------------------------------------------------------------------
__global__ __launch_bounds__(256) void k_prep(
    const float* __restrict__ w_out, const float* __restrict__ w_dist,
    short* __restrict__ wsw, float* __restrict__ wdT)
{
  int gid = blockIdx.x * 256 + threadIdx.x;
  for (int s = gid; s < 32768; s += 16384) {
    int oi = s >> 10, rem = s & 1023, kjg = rem >> 6, l = rem & 63;
    int o = oi * 16 + (l & 15), c = kjg * 32 + (l >> 4) * 8;
    const float* src = w_out + (size_t)o * C_ + c;
    float4 a = *reinterpret_cast<const float4*>(src);
    float4 b = *reinterpret_cast<const float4*>(src + 4);
    uint4 v; v.x = pk2(a.x, a.y); v.y = pk2(a.z, a.w);
    v.z = pk2(b.x, b.y); v.w = pk2(b.z, b.w);
    *reinterpret_cast<uint4*>(wsw + (size_t)s * 8) = v;
  }
  if (gid < C_) {
    wdT[0 * C_ + gid] = w_dist[gid * 3 + 0];
    wdT[1 * C_ + gid] = w_dist[gid * 3 + 1];
    wdT[2 * C_ + gid] = w_dist[gid * 3 + 2];
  }
}

// ---------------------------------------------------------------------------
// k_base: base[bt][c] = temb @ w_time^T + b_time + b_dist   (verified R1-R4)
// ---------------------------------------------------------------------------
__global__ __launch_bounds__(256) void k_base(
    const float* __restrict__ temb, const float* __restrict__ w_time,
    const float* __restrict__ b_time, const float* __restrict__ b_dist,
    float* __restrict__ base)
{
  __shared__ float tt[32][64];
  __shared__ float wt[64][65];
  const int bt0 = blockIdx.x * 32;
  const int c0  = blockIdx.y * 64;
  const int tid = threadIdx.x;
  const int cl  = tid & 63;
  const int g   = tid >> 6;
  float acc[8] = {0.f,0.f,0.f,0.f,0.f,0.f,0.f,0.f};

  for (int k0 = 0; k0 < TEMB_; k0 += 64) {
#pragma unroll
    for (int i = 0; i < 8; ++i) {
      int idx = tid + i * 256; int r = idx >> 6, k = idx & 63;
      tt[r][k] = temb[(size_t)(bt0 + r) * TEMB_ + k0 + k];
    }
#pragma unroll
    for (int i = 0; i < 16; ++i) {
      int idx = tid + i * 256; int r = idx >> 6, k = idx & 63;
      wt[r][k] = w_time[(size_t)(c0 + r) * TEMB_ + k0 + k];
    }
    __syncthreads();
#pragma unroll
    for (int k = 0; k < 64; ++k) {
      float w = wt[cl][k];
#pragma unroll
      for (int j = 0; j < 8; ++j) acc[j] += tt[g + 4 * j][k] * w;
    }
    __syncthreads();
  }
  float bb = b_time[c0 + cl] + b_dist[c0 + cl];
#pragma unroll
  for (int j = 0; j < 8; ++j)
    base[(size_t)(bt0 + g + 4 * j) * C_ + c0 + cl] = acc[j] + bb;
}

// ---------------------------------------------------------------------------
// k_fused: one block per (b,t), 1024 threads (16 waves), ~149 KB LDS.
// Phase 1 (unchanged, verified): R[s=128][o=512] -> Rlds (XOR-swizzled bf16).
// Phase 2 (REWORKED): swap MFMA operands (A = R frags, B = qk frags) so D
//   holds 4 consecutive s per lane; stage each 16d x 128s fp32 chunk into
//   LDS (Rlds reused after brf read; wave-private 8 KB), then flush with
//   fully-contiguous 512 B/row dwordx4 bursts (8 store insts/chunk vs 32
//   scattered dword stores).
// ---------------------------------------------------------------------------
__global__ __launch_bounds__(1024, 4) void k_fused(
    const float* __restrict__ qk, const float* __restrict__ pd,
    const float* __restrict__ base, const float* __restrict__ wdT,
    const short* __restrict__ wsw, const float* __restrict__ b_out,
    float* __restrict__ out)
{
  __shared__ __align__(16) unsigned short Rlds[T_ * C_];  // 128 KB
  __shared__ __align__(16) short At[8192];                // 16 KB
  __shared__ float df[3][T_];

  const int bt = blockIdx.x;
  const int b  = bt >> 7;
  const int t  = bt & 127;
  const int tid  = threadIdx.x;
  const int lane = tid & 63;
  const int wave = tid >> 6;          // 0..15
  const int lanem = lane & 15;
  const int laneg = lane >> 4;

  if (tid < T_) {
    float p = pd[((size_t)b * T_ + t) * T_ + tid];
    df[0][tid] = log1pf(fmaxf(p, 0.f));
    df[1][tid] = log1pf(fmaxf(-p, 0.f));
    df[2][tid] = (p == 0.f) ? 1.f : 0.f;
  }

  // ---------------- Phase 1 (verified R4) ----------------
  const int wm = wave >> 3;
  const int wn = wave & 7;
  const int s_low = tid & 15;
  const int cg    = (tid >> 4) & 7;
  const int si    = tid >> 7;
  const int kjA   = cg >> 2;
  const int cgl   = cg & 3;
  const int laneslotA = s_low + 16 * cgl;
  const int sA    = si * 16 + s_low;
  const float* baserow = base + (size_t)bt * C_;

  f32x4 acc[4][4];
#pragma unroll
  for (int mi = 0; mi < 4; ++mi)
#pragma unroll
    for (int ni = 0; ni < 4; ++ni) acc[mi][ni] = (f32x4){0.f, 0.f, 0.f, 0.f};

  for (int kt = 0; kt < 8; ++kt) {
    __syncthreads();
    short8 b0[4], b1[4];
#pragma unroll
    for (int ni = 0; ni < 4; ++ni)
      b0[ni] = *reinterpret_cast<const short8*>(
          wsw + ((size_t)((wn * 4 + ni) * 16 + kt * 2 + 0) * 64 + lane) * 8);
    {
      const int cglob = kt * 64 + cg * 8;
      const float d0 = df[0][sA], d1 = df[1][sA], d2 = df[2][sA];
      uint4 v;
      {
        float4 bs = *reinterpret_cast<const float4*>(baserow + cglob);
        float4 wa = *reinterpret_cast<const float4*>(wdT + cglob);
        float4 wb = *reinterpret_cast<const float4*>(wdT + C_ + cglob);
        float4 wc = *reinterpret_cast<const float4*>(wdT + 2 * C_ + cglob);
        float x0 = bs.x + d0 * wa.x + d1 * wb.x + d2 * wc.x;
        float x1 = bs.y + d0 * wa.y + d1 * wb.y + d2 * wc.y;
        float x2 = bs.z + d0 * wa.z + d1 * wb.z + d2 * wc.z;
        float x3 = bs.w + d0 * wa.w + d1 * wb.w + d2 * wc.w;
        x0 = x0 / (1.f + __expf(-x0)); x1 = x1 / (1.f + __expf(-x1));
        x2 = x2 / (1.f + __expf(-x2)); x3 = x3 / (1.f + __expf(-x3));
        v.x = pk2(x0, x1); v.y = pk2(x2, x3);
      }
      {
        float4 bs = *reinterpret_cast<const float4*>(baserow + cglob + 4);
        float4 wa = *reinterpret_cast<const float4*>(wdT + cglob + 4);
        float4 wb = *reinterpret_cast<const float4*>(wdT + C_ + cglob + 4);
        float4 wc = *reinterpret_cast<const float4*>(wdT + 2 * C_ + cglob + 4);
        float x0 = bs.x + d0 * wa.x + d1 * wb.x + d2 * wc.x;
        float x1 = bs.y + d0 * wa.y + d1 * wb.y + d2 * wc.y;
        float x2 = bs.z + d0 * wa.z + d1 * wb.z + d2 * wc.z;
        float x3 = bs.w + d0 * wa.w + d1 * wb.w + d2 * wc.w;
        x0 = x0 / (1.f + __expf(-x0)); x1 = x1 / (1.f + __expf(-x1));
        x2 = x2 / (1.f + __expf(-x2)); x3 = x3 / (1.f + __expf(-x3));
        v.z = pk2(x0, x1); v.w = pk2(x2, x3);
      }
      *reinterpret_cast<uint4*>(&At[((si * 2 + kjA) * 64 + laneslotA) * 8]) = v;
    }
#pragma unroll
    for (int ni = 0; ni < 4; ++ni)
      b1[ni] = *reinterpret_cast<const short8*>(
          wsw + ((size_t)((wn * 4 + ni) * 16 + kt * 2 + 1) * 64 + lane) * 8);
    __syncthreads();
    {
      short8 a[4];
#pragma unroll
      for (int mi = 0; mi < 4; ++mi)
        a[mi] = *reinterpret_cast<const short8*>(
            &At[(((wm * 4 + mi) * 2 + 0) * 64 + lane) * 8]);
#pragma unroll
      for (int ni = 0; ni < 4; ++ni)
#pragma unroll
        for (int mi = 0; mi < 4; ++mi)
          acc[mi][ni] = __builtin_amdgcn_mfma_f32_16x16x32_bf16(
              a[mi], b0[ni], acc[mi][ni], 0, 0, 0);
#pragma unroll
      for (int mi = 0; mi < 4; ++mi)
        a[mi] = *reinterpret_cast<const short8*>(
            &At[(((wm * 4 + mi) * 2 + 1) * 64 + lane) * 8]);
#pragma unroll
      for (int ni = 0; ni < 4; ++ni)
#pragma unroll
        for (int mi = 0; mi < 4; ++mi)
          acc[mi][ni] = __builtin_amdgcn_mfma_f32_16x16x32_bf16(
              a[mi], b1[ni], acc[mi][ni], 0, 0, 0);
    }
  }

  // ---- epilogue: + b_out, bf16, swizzled store into Rlds (verified) ----
#pragma unroll
  for (int ni = 0; ni < 4; ++ni) {
    const int o  = wn * 64 + ni * 16 + lanem;
    const float bo = b_out[o];
    const int g  = o >> 3;
#pragma unroll
    for (int mi = 0; mi < 4; ++mi) {
#pragma unroll
      for (int reg = 0; reg < 4; ++reg) {
        int s  = wm * 64 + mi * 16 + laneg * 4 + reg;
        int gp = (g & ~7) | ((g ^ s) & 7);
        Rlds[s * 512 + gp * 8 + (o & 7)] = f2bf(acc[mi][ni][reg] + bo);
      }
    }
  }

  // ---------------- Phase 2: 2 waves per h ----------------
  const int h  = wave >> 1;
  const int dh = wave & 1;
  const size_t HTF = (size_t)H_ * T_ * F_;   // 65536
  const size_t HTT = (size_t)H_ * T_ * T_;   // 131072
  const float* qkb = qk + (size_t)b * D_ * HTF + (size_t)h * T_ * F_ + (size_t)t * F_;
  float* outb = out + (size_t)b * D_ * HTT + (size_t)h * T_ * T_ + (size_t)t * T_;

  // prefetch chunk 0 (independent of Rlds)
  float4 buf[4];
  {
    const float* src = qkb + (size_t)(dh * 128 + lanem) * HTF + laneg * 8;
    buf[0] = *reinterpret_cast<const float4*>(src);
    buf[1] = *reinterpret_cast<const float4*>(src + 4);
    buf[2] = *reinterpret_cast<const float4*>(src + 32);
    buf[3] = *reinterpret_cast<const float4*>(src + 36);
  }
  __syncthreads();   // Rlds ready

  short8 brf[2][8];                    // R frags (A-operand), resident
#pragma unroll
  for (int kj = 0; kj < 2; ++kj)
#pragma unroll
    for (int ni = 0; ni < 8; ++ni) {
      int s  = ni * 16 + lanem;
      int g  = h * 8 + kj * 4 + laneg;
      int gp = (g & ~7) | ((g ^ s) & 7);
      brf[kj][ni] = *reinterpret_cast<const short8*>(&Rlds[s * 512 + gp * 8]);
    }
  __syncthreads();   // all brf reads done -> Rlds reusable as store staging

  // wave-private 8 KB staging region inside Rlds
  char* stO = (char*)Rlds + (size_t)wave * 8192;
  const int xw = lanem << 4;           // stage-write XOR key (row = lanem)
  const int l5 = lane >> 5;            // 0..1 (flush row pair)
  const int sb = (lane & 31) * 16;     // flush byte offset in 512B row

  for (int cc = 0; cc < 8; ++cc) {
    const int dbase = dh * 128 + cc * 16;
    // convert current chunk -> qk B-frags
    short8 qb0, qb1;
    {
      union { uint4 u; short8 s; } cv;
      cv.u.x = pk2(buf[0].x, buf[0].y); cv.u.y = pk2(buf[0].z, buf[0].w);
      cv.u.z = pk2(buf[1].x, buf[1].y); cv.u.w = pk2(buf[1].z, buf[1].w);
      qb0 = cv.s;
      cv.u.x = pk2(buf[2].x, buf[2].y); cv.u.y = pk2(buf[2].z, buf[2].w);
      cv.u.z = pk2(buf[3].x, buf[3].y); cv.u.w = pk2(buf[3].z, buf[3].w);
      qb1 = cv.s;
    }
    // issue next-chunk loads (overlap MFMA + staging + flush)
    if (cc < 7) {
      const float* src = qkb + (size_t)(dbase + 16 + lanem) * HTF + laneg * 8;
      buf[0] = *reinterpret_cast<const float4*>(src);
      buf[1] = *reinterpret_cast<const float4*>(src + 4);
      buf[2] = *reinterpret_cast<const float4*>(src + 32);
      buf[3] = *reinterpret_cast<const float4*>(src + 36);
    }
    // MFMA: D[row=s][col=d], A = R frag, B = qk frag
    f32x4 ac[8];
#pragma unroll
    for (int ni = 0; ni < 8; ++ni) ac[ni] = (f32x4){0.f, 0.f, 0.f, 0.f};
#pragma unroll
    for (int ni = 0; ni < 8; ++ni)
      ac[ni] = __builtin_amdgcn_mfma_f32_16x16x32_bf16(brf[0][ni], qb0, ac[ni], 0, 0, 0);
#pragma unroll
    for (int ni = 0; ni < 8; ++ni)
      ac[ni] = __builtin_amdgcn_mfma_f32_16x16x32_bf16(brf[1][ni], qb1, ac[ni], 0, 0, 0);
    // stage D into LDS: [d=lanem][s], XOR-swizzled 16B granules
#pragma unroll
    for (int ni = 0; ni < 8; ++ni)
      *reinterpret_cast<f32x4*>(
          stO + lanem * 512 + ((ni * 64 + laneg * 16) ^ xw)) = ac[ni];
    // flush: contiguous 512 B per d-row, 2 rows per inst
#pragma unroll
    for (int i = 0; i < 8; ++i) {
      int r = i * 2 + l5;
      float4 v = *reinterpret_cast<const float4*>(
          stO + r * 512 + (sb ^ (r << 4)));
      *reinterpret_cast<float4*>(
          outb + (size_t)(dbase + r) * HTT + (lane & 31) * 4) = v;
    }
  }
}

extern "C" void kernel_launch(void* const* d_in, const int* in_sizes, int n_in,
                              void* d_out, int out_size, void* d_ws, size_t ws_size,
                              hipStream_t stream) {
  const float* qk     = (const float*)d_in[0];
  const float* pd     = (const float*)d_in[1];
  const float* temb   = (const float*)d_in[2];
  const float* w_dist = (const float*)d_in[3];
  const float* b_dist = (const float*)d_in[4];
  const float* w_time = (const float*)d_in[5];
  const float* b_time = (const float*)d_in[6];
  const float* w_out  = (const float*)d_in[7];
  const float* b_out  = (const float*)d_in[8];
  float* out = (float*)d_out;

  char* ws = (char*)d_ws;
  float* base = (float*)(ws);              // 524288 B
  float* wdT  = (float*)(ws + 524288);     //   6144 B (8 KB slot)
  short* wsw  = (short*)(ws + 532480);     // 524288 B

  hipLaunchKernelGGL(k_prep, dim3(64), dim3(256), 0, stream,
                     w_out, w_dist, wsw, wdT);
  hipLaunchKernelGGL(k_base, dim3(8, 8), dim3(256), 0, stream,
                     temb, w_time, b_time, b_dist, base);
  hipLaunchKernelGGL(k_fused, dim3(B_ * T_), dim3(1024), 0, stream,
                     qk, pd, base, wdT, wsw, b_out, out);
}